// Round 1
// baseline (300.871 us; speedup 1.0000x reference)
//
#include <hip/hip_runtime.h>
#include <hip/hip_bf16.h>

typedef __attribute__((ext_vector_type(8))) short bf16x8;
typedef __attribute__((ext_vector_type(4))) float f32x4;

#define MFMA16(a,b,c) __builtin_amdgcn_mfma_f32_16x16x32_bf16((a),(b),(c),0,0,0)

static constexpr int S_ = 2048, E_ = 1024, H_ = 16;

// ---------------- prep kernels ----------------

__global__ void conv_bf16_k(const float* __restrict__ src, __hip_bfloat16* __restrict__ dst, int n4) {
  int i = blockIdx.x * blockDim.x + threadIdx.x;
  if (i < n4) {
    float4 v = reinterpret_cast<const float4*>(src)[i];
    dst[4*i+0] = __float2bfloat16(v.x);
    dst[4*i+1] = __float2bfloat16(v.y);
    dst[4*i+2] = __float2bfloat16(v.z);
    dst[4*i+3] = __float2bfloat16(v.w);
  }
}

// W [k][n] f32 -> WT [n][k] bf16
__global__ __launch_bounds__(256) void wtrans_k(const float* __restrict__ W, __hip_bfloat16* __restrict__ WT) {
  __shared__ float tile[64][65];
  int bx = blockIdx.x, by = blockIdx.y, tid = threadIdx.x;
  for (int i = tid; i < 4096; i += 256) {
    int ki = i >> 6, ni = i & 63;
    tile[ki][ni] = W[(size_t)(by*64+ki)*E_ + bx*64 + ni];
  }
  __syncthreads();
  for (int i = tid; i < 4096; i += 256) {
    int ni = i >> 6, ki = i & 63;
    WT[(size_t)(bx*64+ni)*E_ + by*64 + ki] = __float2bfloat16(tile[ki][ni]);
  }
}

__global__ void rope_table_k(float* __restrict__ cost, float* __restrict__ sint) {
  int idx = blockIdx.x*256 + threadIdx.x;  // idx = s*32 + f
  int f = idx & 31;
  int s = idx >> 5;
  float inv = powf(10000.f, -(float)f * (1.f/32.f));
  float a = (float)s * inv;
  cost[idx] = cosf(a);
  sint[idx] = sinf(a);
}

// ---------------- GEMM: C[m][n] = sum_k A[m][k]*BT[n][k] + bias[n] ----------------
// A: M x K bf16 row-major, BT: N x K bf16 row-major, C: M x N f32. BM=BN=128, BK=64.
__global__ __launch_bounds__(256) void gemm_bt_k(const __hip_bfloat16* __restrict__ A,
                                                 const __hip_bfloat16* __restrict__ BT,
                                                 const float* __restrict__ bias,
                                                 float* __restrict__ C,
                                                 int M, int N, int K) {
  __shared__ __hip_bfloat16 As[128][72];
  __shared__ __hip_bfloat16 Bs[128][72];
  int tid = threadIdx.x, lane = tid & 63, w = tid >> 6;
  int m0 = blockIdx.y * 128, n0 = blockIdx.x * 128;
  int wr = (w >> 1) * 64, wc = (w & 1) * 64;
  f32x4 acc[4][4] = {};
  int r = tid >> 1;
  int cb = (tid & 1) * 32;
  int rowq = lane & 15, ksel = (lane >> 4) << 3;
  for (int k0 = 0; k0 < K; k0 += 64) {
    __syncthreads();
    const __hip_bfloat16* Ap = A + (size_t)(m0 + r) * K + k0 + cb;
    const __hip_bfloat16* Bp = BT + (size_t)(n0 + r) * K + k0 + cb;
    *(int4*)&As[r][cb +  0] = *(const int4*)(Ap +  0);
    *(int4*)&As[r][cb +  8] = *(const int4*)(Ap +  8);
    *(int4*)&As[r][cb + 16] = *(const int4*)(Ap + 16);
    *(int4*)&As[r][cb + 24] = *(const int4*)(Ap + 24);
    *(int4*)&Bs[r][cb +  0] = *(const int4*)(Bp +  0);
    *(int4*)&Bs[r][cb +  8] = *(const int4*)(Bp +  8);
    *(int4*)&Bs[r][cb + 16] = *(const int4*)(Bp + 16);
    *(int4*)&Bs[r][cb + 24] = *(const int4*)(Bp + 24);
    __syncthreads();
    for (int kk = 0; kk < 64; kk += 32) {
      bf16x8 a[4], b[4];
      for (int i = 0; i < 4; ++i) a[i] = *(const bf16x8*)&As[wr + i*16 + rowq][kk + ksel];
      for (int i = 0; i < 4; ++i) b[i] = *(const bf16x8*)&Bs[wc + i*16 + rowq][kk + ksel];
      for (int i = 0; i < 4; ++i)
        for (int j = 0; j < 4; ++j)
          acc[i][j] = MFMA16(a[i], b[j], acc[i][j]);
    }
  }
  for (int i = 0; i < 4; ++i)
    for (int j = 0; j < 4; ++j) {
      int row = m0 + wr + i*16 + ((lane >> 4) << 2);
      int col = n0 + wc + j*16 + rowq;
      float bv = bias[col];
      for (int rg = 0; rg < 4; ++rg)
        C[(size_t)(row + rg) * N + col] = acc[i][j][rg] + bv;
    }
}

// ---------------- rotary + head-major layout ----------------
// q_raw/k_raw: [S][E] f32 (bias already added). out: [H][S][64] bf16, rotated.
__global__ void rope_apply_k(const float* __restrict__ q_raw, const float* __restrict__ k_raw,
                             const float* __restrict__ cost, const float* __restrict__ sint,
                             __hip_bfloat16* __restrict__ qh, __hip_bfloat16* __restrict__ kh) {
  int idx = blockIdx.x * 256 + threadIdx.x;   // (s, h, f)
  int f = idx & 31, h = (idx >> 5) & 15, s = idx >> 9;
  float c = cost[s*32+f], sn = sint[s*32+f];
  size_t src = (size_t)s * E_ + h*64 + f;
  size_t dst = ((size_t)h * S_ + s) * 64 + f;
  float q1 = q_raw[src], q2 = q_raw[src + 32];
  qh[dst]      = __float2bfloat16(q1*c - q2*sn);
  qh[dst + 32] = __float2bfloat16(q2*c + q1*sn);
  float k1 = k_raw[src], k2 = k_raw[src + 32];
  kh[dst]      = __float2bfloat16(k1*c - k2*sn);
  kh[dst + 32] = __float2bfloat16(k2*c + k1*sn);
}

// v_raw [S][E] f32 -> vt [H][64][S] bf16 (V transposed per head)
__global__ __launch_bounds__(256) void vtrans_k(const float* __restrict__ v_raw, const float* __restrict__ bv,
                                                __hip_bfloat16* __restrict__ vt) {
  __shared__ float tile[64][65];
  int sb = blockIdx.x, h = blockIdx.y, tid = threadIdx.x;
  for (int i = tid; i < 4096; i += 256) {
    int si = i >> 6, di = i & 63;
    tile[si][di] = v_raw[(size_t)(sb*64+si)*E_ + h*64 + di] + bv[h*64+di];
  }
  __syncthreads();
  for (int i = tid; i < 4096; i += 256) {
    int di = i >> 6, si = i & 63;
    vt[((size_t)h*64 + di)*S_ + sb*64 + si] = __float2bfloat16(tile[si][di]);
  }
}

// ---------------- fused causal attention with rel-pos bias ----------------
// qh,kh: [H][S][64] bf16 (rotated); vt: [H][64][S] bf16; relb: [4095][64] bf16
// out: attn_out [S][E] bf16
__global__ __launch_bounds__(256) void attn_k(const __hip_bfloat16* __restrict__ qh,
                                              const __hip_bfloat16* __restrict__ kh,
                                              const __hip_bfloat16* __restrict__ vt,
                                              const __hip_bfloat16* __restrict__ relb,
                                              __hip_bfloat16* __restrict__ attn_out) {
  int h = blockIdx.y;
  int qb = gridDim.x - 1 - blockIdx.x;    // heavy blocks first
  int tid = threadIdx.x, lane = tid & 63, w = tid >> 6;
  int i0w = qb*64 + w*16;                 // this wave's first query row
  __shared__ __hip_bfloat16 Ks[64][72];
  __shared__ __hip_bfloat16 Vs[64][72];   // Vs[d][key]
  __shared__ float Wt[4][16][84];
  __shared__ __hip_bfloat16 Ps[4][16][80];
  int rowq = lane & 15, ksel = (lane >> 4) << 3, hi = lane >> 4;

  const __hip_bfloat16* qrow = qh + ((size_t)h*S_ + i0w + rowq)*64 + ksel;
  bf16x8 q0 = *(const bf16x8*)(qrow);
  bf16x8 q1 = *(const bf16x8*)(qrow + 32);

  f32x4 o[4] = {};
  float mrow[4], lrow[4];
  for (int i = 0; i < 4; ++i) { mrow[i] = -1e30f; lrow[i] = 0.f; }

  int rstage = tid >> 2, cstage = (tid & 3) * 8;
  int nt = qb + 1;
  for (int t = 0; t < nt; ++t) {
    int j0 = t * 64;
    __syncthreads();
    const __hip_bfloat16* kp = kh + ((size_t)h*S_ + j0 + rstage)*64 + cstage;
    *(int4*)&Ks[rstage][cstage]      = *(const int4*)kp;
    *(int4*)&Ks[rstage][cstage + 32] = *(const int4*)(kp + 32);
    const __hip_bfloat16* vp = vt + ((size_t)h*64 + rstage)*S_ + j0 + cstage;
    *(int4*)&Vs[rstage][cstage]      = *(const int4*)vp;
    *(int4*)&Vs[rstage][cstage + 32] = *(const int4*)(vp + 32);
    __syncthreads();

    // scores (QK^T) and rel window Wt[r][c] = q[r] . relb[base + c]
    f32x4 sa[4] = {};
    f32x4 wtacc[5] = {};
    int base = j0 - i0w + 2032;   // 2047 - 15
    for (int kk = 0; kk < 2; ++kk) {
      bf16x8 a = kk ? q1 : q0;
      for (int nf = 0; nf < 4; ++nf) {
        bf16x8 b = *(const bf16x8*)&Ks[nf*16 + rowq][kk*32 + ksel];
        sa[nf] = MFMA16(a, b, sa[nf]);
      }
      for (int nf = 0; nf < 5; ++nf) {
        const __hip_bfloat16* rp = relb + (size_t)(base + nf*16 + rowq)*64 + kk*32 + ksel;
        bf16x8 b = *(const bf16x8*)rp;
        wtacc[nf] = MFMA16(a, b, wtacc[nf]);
      }
    }
    for (int nf = 0; nf < 5; ++nf)
      for (int rg = 0; rg < 4; ++rg)
        Wt[w][hi*4 + rg][nf*16 + rowq] = wtacc[nf][rg];

    // online softmax (rows live in 16-lane groups)
    float alpha[4];
    bool last = (t == nt - 1);
    for (int rg = 0; rg < 4; ++rg) {
      int row = hi*4 + rg;
      float sv[4];
      float tm = -1e30f;
      for (int nf = 0; nf < 4; ++nf) {
        int s = nf*16 + rowq;
        float v = sa[nf][rg] * 0.125f + Wt[w][row][s - row + 15];
        if (last && s > w*16 + row) v = -1e30f;
        sv[nf] = v;
        tm = fmaxf(tm, v);
      }
      for (int mk = 1; mk < 16; mk <<= 1) tm = fmaxf(tm, __shfl_xor(tm, mk));
      float mnew = fmaxf(mrow[rg], tm);
      float al = __expf(mrow[rg] - mnew);
      float ls = 0.f;
      for (int nf = 0; nf < 4; ++nf) {
        float p = __expf(sv[nf] - mnew);
        ls += p;
        Ps[w][row][nf*16 + rowq] = __float2bfloat16(p);
      }
      for (int mk = 1; mk < 16; mk <<= 1) ls += __shfl_xor(ls, mk);
      lrow[rg] = lrow[rg] * al + ls;
      mrow[rg] = mnew;
      alpha[rg] = al;
    }
    for (int df = 0; df < 4; ++df)
      for (int rg = 0; rg < 4; ++rg) o[df][rg] *= alpha[rg];

    // PV: o += P @ V   (A = Ps rows=q, k=key; B = Vs[d][key])
    for (int kk = 0; kk < 2; ++kk) {
      bf16x8 a = *(const bf16x8*)&Ps[w][rowq][kk*32 + ksel];
      for (int df = 0; df < 4; ++df) {
        bf16x8 b = *(const bf16x8*)&Vs[df*16 + rowq][kk*32 + ksel];
        o[df] = MFMA16(a, b, o[df]);
      }
    }
  }

  for (int df = 0; df < 4; ++df)
    for (int rg = 0; rg < 4; ++rg) {
      int row = i0w + hi*4 + rg;
      int col = h*64 + df*16 + rowq;
      attn_out[(size_t)row * E_ + col] = __float2bfloat16(o[df][rg] / lrow[rg]);
    }
}

// ---------------- launcher ----------------

extern "C" void kernel_launch(void* const* d_in, const int* in_sizes, int n_in,
                              void* d_out, int out_size, void* d_ws, size_t ws_size,
                              hipStream_t stream) {
  const float* x   = (const float*)d_in[0];
  const float* Wq  = (const float*)d_in[2];
  const float* bq  = (const float*)d_in[3];
  const float* Wk  = (const float*)d_in[4];
  const float* bk  = (const float*)d_in[5];
  const float* Wv  = (const float*)d_in[6];
  const float* bv  = (const float*)d_in[7];
  const float* Wo  = (const float*)d_in[8];
  const float* bo  = (const float*)d_in[9];
  const float* rel = (const float*)d_in[10];
  float* out = (float*)d_out;

  char* ws = (char*)d_ws;
  size_t off = 0;
  auto alloc = [&](size_t bytes) -> void* {
    void* p = ws + off;
    off = (off + bytes + 255) & ~(size_t)255;
    return p;
  };
  __hip_bfloat16* xb   = (__hip_bfloat16*)alloc((size_t)S_*E_*2);
  __hip_bfloat16* wqT  = (__hip_bfloat16*)alloc((size_t)E_*E_*2);
  __hip_bfloat16* wkT  = (__hip_bfloat16*)alloc((size_t)E_*E_*2);
  __hip_bfloat16* wvT  = (__hip_bfloat16*)alloc((size_t)E_*E_*2);
  __hip_bfloat16* woT  = (__hip_bfloat16*)alloc((size_t)E_*E_*2);
  __hip_bfloat16* relb = (__hip_bfloat16*)alloc((size_t)4095*64*2);
  float* cost = (float*)alloc((size_t)S_*32*4);
  float* sint = (float*)alloc((size_t)S_*32*4);
  float* q_raw = (float*)alloc((size_t)S_*E_*4);
  float* k_raw = (float*)alloc((size_t)S_*E_*4);
  float* v_raw = (float*)alloc((size_t)S_*E_*4);
  __hip_bfloat16* qhh = (__hip_bfloat16*)alloc((size_t)S_*E_*2);
  __hip_bfloat16* khh = (__hip_bfloat16*)alloc((size_t)S_*E_*2);
  __hip_bfloat16* vth = (__hip_bfloat16*)alloc((size_t)S_*E_*2);
  __hip_bfloat16* aout = (__hip_bfloat16*)alloc((size_t)S_*E_*2);

  // prep
  conv_bf16_k<<<(S_*E_/4 + 255)/256, 256, 0, stream>>>(x, xb, S_*E_/4);
  conv_bf16_k<<<(4095*64/4 + 255)/256, 256, 0, stream>>>(rel, relb, 4095*64/4);
  wtrans_k<<<dim3(16,16), 256, 0, stream>>>(Wq, wqT);
  wtrans_k<<<dim3(16,16), 256, 0, stream>>>(Wk, wkT);
  wtrans_k<<<dim3(16,16), 256, 0, stream>>>(Wv, wvT);
  wtrans_k<<<dim3(16,16), 256, 0, stream>>>(Wo, woT);
  rope_table_k<<<S_*32/256, 256, 0, stream>>>(cost, sint);

  // QKV projections
  gemm_bt_k<<<dim3(8,16), 256, 0, stream>>>(xb, wqT, bq, q_raw, S_, E_, E_);
  gemm_bt_k<<<dim3(8,16), 256, 0, stream>>>(xb, wkT, bk, k_raw, S_, E_, E_);
  gemm_bt_k<<<dim3(8,16), 256, 0, stream>>>(xb, wvT, bv, v_raw, S_, E_, E_);

  // rotary + layout
  rope_apply_k<<<(S_*H_*32)/256, 256, 0, stream>>>(q_raw, k_raw, cost, sint, qhh, khh);
  vtrans_k<<<dim3(S_/64, H_), 256, 0, stream>>>(v_raw, bv, vth);

  // attention
  attn_k<<<dim3(S_/64, H_), 256, 0, stream>>>(qhh, khh, vth, relb, aout);

  // output projection
  gemm_bt_k<<<dim3(8,16), 256, 0, stream>>>(aout, woT, bo, out, S_, E_, E_);
}

// Round 2
// 197.994 us; speedup vs baseline: 1.5196x; 1.5196x over previous
//
#include <hip/hip_runtime.h>
#include <hip/hip_bf16.h>

typedef __attribute__((ext_vector_type(8))) short bf16x8;
typedef __attribute__((ext_vector_type(4))) float f32x4;

#define MFMA16(a,b,c) __builtin_amdgcn_mfma_f32_16x16x32_bf16((a),(b),(c),0,0,0)
#define GLDS16(g, l) __builtin_amdgcn_global_load_lds((const __attribute__((address_space(1))) void*)(g), (__attribute__((address_space(3))) void*)(l), 16, 0, 0)

static constexpr int S_ = 2048, E_ = 1024, H_ = 16;

// ---------------- prep kernels ----------------

__global__ void conv_bf16_k(const float* __restrict__ src, __hip_bfloat16* __restrict__ dst, int n4) {
  int i = blockIdx.x * blockDim.x + threadIdx.x;
  if (i < n4) {
    float4 v = reinterpret_cast<const float4*>(src)[i];
    dst[4*i+0] = __float2bfloat16(v.x);
    dst[4*i+1] = __float2bfloat16(v.y);
    dst[4*i+2] = __float2bfloat16(v.z);
    dst[4*i+3] = __float2bfloat16(v.w);
  }
}

// W [k][n] f32 -> WT [n][k] bf16
__global__ __launch_bounds__(256) void wtrans_k(const float* __restrict__ W, __hip_bfloat16* __restrict__ WT) {
  __shared__ float tile[64][65];
  int bx = blockIdx.x, by = blockIdx.y, tid = threadIdx.x;
  for (int i = tid; i < 4096; i += 256) {
    int ki = i >> 6, ni = i & 63;
    tile[ki][ni] = W[(size_t)(by*64+ki)*E_ + bx*64 + ni];
  }
  __syncthreads();
  for (int i = tid; i < 4096; i += 256) {
    int ni = i >> 6, ki = i & 63;
    WT[(size_t)(bx*64+ni)*E_ + by*64 + ki] = __float2bfloat16(tile[ki][ni]);
  }
}

__global__ void rope_table_k(float* __restrict__ cost, float* __restrict__ sint) {
  int idx = blockIdx.x*256 + threadIdx.x;  // idx = s*32 + f
  int f = idx & 31;
  int s = idx >> 5;
  float inv = powf(10000.f, -(float)f * (1.f/32.f));
  float a = (float)s * inv;
  cost[idx] = cosf(a);
  sint[idx] = sinf(a);
}

__global__ void bias_concat_k(const float* __restrict__ bq, const float* __restrict__ bk,
                              const float* __restrict__ bv, float* __restrict__ bqkv) {
  int i = blockIdx.x*256 + threadIdx.x;
  if (i < 3072) bqkv[i] = i < 1024 ? bq[i] : (i < 2048 ? bk[i-1024] : bv[i-2048]);
}

// ---------------- GEMM core: C = A @ BT^T, double-buffered global_load_lds ----------------
// MODE 0: fused QKV epilogue (rope for q/k -> [H][S][64] bf16; v -> [S][E] bf16)
// MODE 1: f32 out + bias
template<int BM, int MODE>
__global__ __launch_bounds__(256) void gemm_k(const __hip_bfloat16* __restrict__ A,
                                              const __hip_bfloat16* __restrict__ BT,
                                              const float* __restrict__ bias,
                                              const float* __restrict__ cost,
                                              const float* __restrict__ sint,
                                              __hip_bfloat16* __restrict__ qhh,
                                              __hip_bfloat16* __restrict__ khh,
                                              __hip_bfloat16* __restrict__ vb,
                                              float* __restrict__ outf,
                                              int K) {
  constexpr int MI = BM/32;
  __shared__ __hip_bfloat16 As[2][BM*64];
  __shared__ __hip_bfloat16 Bs[2][128*64];
  int tid = threadIdx.x, lane = tid & 63, w = tid >> 6;
  int rowq = lane & 15, hi = lane >> 4, ksel = hi << 3;
  int wr = (w >> 1) * (BM/2), wc = (w & 1) * 64;
  int m0 = blockIdx.y * BM, n0 = blockIdx.x * 128;
  int l3 = lane >> 3, l7 = lane & 7;
  f32x4 acc[MI][4] = {};

  auto stage = [&](int k0, int buf) {
    const char* Ap = (const char*)A + ((size_t)(m0 + w*(BM/4)) * K + k0) * 2;
    const char* Bp = (const char*)BT + ((size_t)(n0 + w*32) * K + k0) * 2;
    char* Ad = (char*)&As[buf][w*(BM/4)*64];
    char* Bd = (char*)&Bs[buf][w*32*64];
    for (int i = 0; i < MI; ++i)
      GLDS16(Ap + (size_t)(i*8 + l3)*(K*2) + l7*16, Ad + i*1024);
    for (int i = 0; i < 4; ++i)
      GLDS16(Bp + (size_t)(i*8 + l3)*(K*2) + l7*16, Bd + i*1024);
  };

  stage(0, 0);
  __syncthreads();
  int buf = 0;
  int nk = K >> 6;
  for (int t = 0; t < nk; ++t) {
    if (t + 1 < nk) stage((t+1)*64, buf^1);
    for (int kk = 0; kk < 64; kk += 32) {
      bf16x8 a[MI], b[4];
      for (int i = 0; i < MI; ++i) a[i] = *(const bf16x8*)&As[buf][(wr + i*16 + rowq)*64 + kk + ksel];
      for (int j = 0; j < 4; ++j)  b[j] = *(const bf16x8*)&Bs[buf][(wc + j*16 + rowq)*64 + kk + ksel];
      for (int i = 0; i < MI; ++i)
        for (int j = 0; j < 4; ++j)
          acc[i][j] = MFMA16(a[i], b[j], acc[i][j]);
    }
    __syncthreads();
    buf ^= 1;
  }

  if constexpr (MODE == 0) {
    int matsel = n0 >> 10, ncol = n0 & 1023;
    float bcol[4];
    for (int j = 0; j < 4; ++j) bcol[j] = bias[n0 + wc + j*16 + rowq];
    if (matsel < 2) {
      __hip_bfloat16* dst = matsel ? khh : qhh;
      for (int i = 0; i < MI; ++i)
        for (int rg = 0; rg < 4; ++rg) {
          int s = m0 + wr + i*16 + hi*4 + rg;
          for (int j = 0; j < 2; ++j) {
            int colp = ncol + wc + j*16 + rowq;
            int hh = colp >> 6, f = colp & 31;
            float c = cost[s*32 + f], sn = sint[s*32 + f];
            float v1 = acc[i][j][rg]   + bcol[j];
            float v2 = acc[i][j+2][rg] + bcol[j+2];
            dst[((size_t)hh*S_ + s)*64 + f]      = __float2bfloat16(v1*c - v2*sn);
            dst[((size_t)hh*S_ + s)*64 + f + 32] = __float2bfloat16(v2*c + v1*sn);
          }
        }
    } else {
      for (int i = 0; i < MI; ++i)
        for (int rg = 0; rg < 4; ++rg) {
          int s = m0 + wr + i*16 + hi*4 + rg;
          for (int j = 0; j < 4; ++j)
            vb[(size_t)s*E_ + ncol + wc + j*16 + rowq] = __float2bfloat16(acc[i][j][rg] + bcol[j]);
        }
    }
  } else {
    for (int i = 0; i < MI; ++i)
      for (int rg = 0; rg < 4; ++rg) {
        int row = m0 + wr + i*16 + hi*4 + rg;
        for (int j = 0; j < 4; ++j) {
          int col = n0 + wc + j*16 + rowq;
          outf[(size_t)row*E_ + col] = acc[i][j][rg] + bias[col];
        }
      }
  }
}

// vb [S][E] bf16 -> vt [H][64][S] bf16
__global__ __launch_bounds__(256) void vtrans_k(const __hip_bfloat16* __restrict__ vb,
                                                __hip_bfloat16* __restrict__ vt) {
  __shared__ __hip_bfloat16 tile[64][72];
  int sb = blockIdx.x, h = blockIdx.y, tid = threadIdx.x;
  int r = tid >> 3, c = (tid & 7) * 8;
  *(int4*)&tile[r][c]    = *(const int4*)(vb + (size_t)(sb*64 + r)*E_ + h*64 + c);
  *(int4*)&tile[r+32][c] = *(const int4*)(vb + (size_t)(sb*64 + r+32)*E_ + h*64 + c);
  __syncthreads();
  int d = tid >> 3, s0 = (tid & 7) * 8;
  __hip_bfloat16 bufa[8], bufb[8];
  for (int j = 0; j < 8; ++j) bufa[j] = tile[s0+j][d];
  for (int j = 0; j < 8; ++j) bufb[j] = tile[s0+j][d+32];
  *(int4*)(vt + ((size_t)h*64 + d)*S_ + sb*64 + s0)    = *(int4*)bufa;
  *(int4*)(vt + ((size_t)h*64 + d+32)*S_ + sb*64 + s0) = *(int4*)bufb;
}

// ---------------- fused causal attention with rel-pos bias ----------------
// qh,kh: [H][S][64] bf16 (rotated); vt: [H][64][S]; relb: [4095][64]; out: [S][E] bf16
__global__ __launch_bounds__(256) void attn_k(const __hip_bfloat16* __restrict__ qh,
                                              const __hip_bfloat16* __restrict__ kh,
                                              const __hip_bfloat16* __restrict__ vt,
                                              const __hip_bfloat16* __restrict__ relb,
                                              __hip_bfloat16* __restrict__ attn_out) {
  int h = blockIdx.y;
  int qb = gridDim.x - 1 - blockIdx.x;    // heavy blocks first
  int tid = threadIdx.x, lane = tid & 63, w = tid >> 6;
  int i0w = qb*64 + w*16;
  __shared__ __hip_bfloat16 Ks[2][4096];  // [64][64] linear, XOR-swizzled content
  __shared__ __hip_bfloat16 Vs[2][4096];  // [d][key] linear, XOR-swizzled content
  __shared__ float Wt[4][16][80];
  __shared__ __hip_bfloat16 Ps[4][16][88];
  int rowq = lane & 15, hi = lane >> 4, ksel = hi << 3;
  int l3 = lane >> 3, l7 = lane & 7;
  int swz = (l7*16) ^ (l3 << 4);          // inverse-swizzled source byte-col

  const __hip_bfloat16* qrow = qh + ((size_t)h*S_ + i0w + rowq)*64 + ksel;
  bf16x8 q0 = *(const bf16x8*)(qrow);
  bf16x8 q1 = *(const bf16x8*)(qrow + 32);

  f32x4 o[4] = {};
  float mrow[4], lrow[4];
  for (int i = 0; i < 4; ++i) { mrow[i] = -1e30f; lrow[i] = 0.f; }

  auto stage = [&](int t, int buf) {
    int j0 = t * 64;
    const char* kp = (const char*)(kh + ((size_t)h*S_ + j0 + w*16)*64);
    const char* vp = (const char*)(vt + ((size_t)(h*64 + w*16))*S_ + j0);
    char* kd = (char*)&Ks[buf][w*16*64];
    char* vd = (char*)&Vs[buf][w*16*64];
    for (int i = 0; i < 2; ++i) {
      GLDS16(kp + (size_t)(i*8 + l3)*128  + swz, kd + i*1024);
      GLDS16(vp + (size_t)(i*8 + l3)*4096 + swz, vd + i*1024);
    }
  };

  // swizzled frag col (bytes -> elems) for ds_read: logical (kk*64 + hi*16) ^ ((rowq&7)<<4)
  int pcol0 = ((hi*16)      ^ ((rowq & 7) << 4)) >> 1;
  int pcol1 = ((64 + hi*16) ^ ((rowq & 7) << 4)) >> 1;

  int nt = qb + 1;
  stage(0, 0);
  __syncthreads();
  int buf = 0;
  for (int t = 0; t < nt; ++t) {
    int j0 = t * 64;
    if (t + 1 < nt) stage(t+1, buf^1);

    // QK^T and rel window: Wt[r][c] = q[r] . relb[base + c]
    f32x4 sa[4] = {};
    f32x4 wtacc[5] = {};
    int base = j0 - i0w + 2032;   // 2047 - 15
    for (int kk = 0; kk < 2; ++kk) {
      bf16x8 a = kk ? q1 : q0;
      int pc = kk ? pcol1 : pcol0;
      for (int nf = 0; nf < 4; ++nf) {
        bf16x8 b = *(const bf16x8*)&Ks[buf][(nf*16 + rowq)*64 + pc];
        sa[nf] = MFMA16(a, b, sa[nf]);
      }
      for (int nf = 0; nf < 5; ++nf) {
        const __hip_bfloat16* rp = relb + (size_t)(base + nf*16 + rowq)*64 + kk*32 + ksel;
        wtacc[nf] = MFMA16(a, *(const bf16x8*)rp, wtacc[nf]);
      }
    }
    for (int nf = 0; nf < 5; ++nf)
      for (int rg = 0; rg < 4; ++rg)
        Wt[w][hi*4 + rg][nf*16 + rowq] = wtacc[nf][rg];

    // online softmax (rows live in 16-lane groups); Wt/Ps per-wave private, no barrier
    float alpha[4];
    bool last = (t == nt - 1);
    for (int rg = 0; rg < 4; ++rg) {
      int row = hi*4 + rg;
      float sv[4];
      float tm = -1e30f;
      for (int nf = 0; nf < 4; ++nf) {
        int s = nf*16 + rowq;
        float v = sa[nf][rg] * 0.125f + Wt[w][row][s - row + 15];
        if (last && s > w*16 + row) v = -1e30f;
        sv[nf] = v;
        tm = fmaxf(tm, v);
      }
      for (int mk = 1; mk < 16; mk <<= 1) tm = fmaxf(tm, __shfl_xor(tm, mk));
      float mnew = fmaxf(mrow[rg], tm);
      float al = __expf(mrow[rg] - mnew);
      float ls = 0.f;
      for (int nf = 0; nf < 4; ++nf) {
        float p = __expf(sv[nf] - mnew);
        ls += p;
        Ps[w][row][nf*16 + rowq] = __float2bfloat16(p);
      }
      for (int mk = 1; mk < 16; mk <<= 1) ls += __shfl_xor(ls, mk);
      lrow[rg] = lrow[rg] * al + ls;
      mrow[rg] = mnew;
      alpha[rg] = al;
    }
    for (int df = 0; df < 4; ++df)
      for (int rg = 0; rg < 4; ++rg) o[df][rg] *= alpha[rg];

    // PV: o += P @ V
    for (int kk = 0; kk < 2; ++kk) {
      bf16x8 a = *(const bf16x8*)&Ps[w][rowq][kk*32 + ksel];
      int pc = kk ? pcol1 : pcol0;
      for (int df = 0; df < 4; ++df) {
        bf16x8 b = *(const bf16x8*)&Vs[buf][(df*16 + rowq)*64 + pc];
        o[df] = MFMA16(a, b, o[df]);
      }
    }
    __syncthreads();
    buf ^= 1;
  }

  for (int df = 0; df < 4; ++df)
    for (int rg = 0; rg < 4; ++rg) {
      int row = i0w + hi*4 + rg;
      int col = h*64 + df*16 + rowq;
      attn_out[(size_t)row * E_ + col] = __float2bfloat16(o[df][rg] / lrow[rg]);
    }
}

// ---------------- launcher ----------------

extern "C" void kernel_launch(void* const* d_in, const int* in_sizes, int n_in,
                              void* d_out, int out_size, void* d_ws, size_t ws_size,
                              hipStream_t stream) {
  const float* x   = (const float*)d_in[0];
  const float* Wq  = (const float*)d_in[2];
  const float* bq  = (const float*)d_in[3];
  const float* Wk  = (const float*)d_in[4];
  const float* bk  = (const float*)d_in[5];
  const float* Wv  = (const float*)d_in[6];
  const float* bv  = (const float*)d_in[7];
  const float* Wo  = (const float*)d_in[8];
  const float* bo  = (const float*)d_in[9];
  const float* rel = (const float*)d_in[10];
  float* out = (float*)d_out;

  char* ws = (char*)d_ws;
  size_t off = 0;
  auto alloc = [&](size_t bytes) -> void* {
    void* p = ws + off;
    off = (off + bytes + 255) & ~(size_t)255;
    return p;
  };
  __hip_bfloat16* xb    = (__hip_bfloat16*)alloc((size_t)S_*E_*2);
  __hip_bfloat16* wqkvT = (__hip_bfloat16*)alloc((size_t)3*E_*E_*2);
  __hip_bfloat16* woT   = (__hip_bfloat16*)alloc((size_t)E_*E_*2);
  __hip_bfloat16* relb  = (__hip_bfloat16*)alloc((size_t)4095*64*2);
  float* bqkv = (float*)alloc((size_t)3072*4);
  float* cost = (float*)alloc((size_t)S_*32*4);
  float* sint = (float*)alloc((size_t)S_*32*4);
  __hip_bfloat16* qhh  = (__hip_bfloat16*)alloc((size_t)S_*E_*2);
  __hip_bfloat16* khh  = (__hip_bfloat16*)alloc((size_t)S_*E_*2);
  __hip_bfloat16* vbuf = (__hip_bfloat16*)alloc((size_t)S_*E_*2);
  __hip_bfloat16* vth  = (__hip_bfloat16*)alloc((size_t)S_*E_*2);
  __hip_bfloat16* aout = (__hip_bfloat16*)alloc((size_t)S_*E_*2);

  conv_bf16_k<<<(S_*E_/4 + 255)/256, 256, 0, stream>>>(x, xb, S_*E_/4);
  conv_bf16_k<<<(4095*64/4 + 255)/256, 256, 0, stream>>>(rel, relb, 4095*64/4);
  wtrans_k<<<dim3(16,16), 256, 0, stream>>>(Wq, wqkvT);
  wtrans_k<<<dim3(16,16), 256, 0, stream>>>(Wk, wqkvT + (size_t)E_*E_);
  wtrans_k<<<dim3(16,16), 256, 0, stream>>>(Wv, wqkvT + (size_t)2*E_*E_);
  wtrans_k<<<dim3(16,16), 256, 0, stream>>>(Wo, woT);
  bias_concat_k<<<12, 256, 0, stream>>>(bq, bk, bv, bqkv);
  rope_table_k<<<S_*32/256, 256, 0, stream>>>(cost, sint);

  // fused QKV projection + rope + layout
  gemm_k<128,0><<<dim3(24,16), 256, 0, stream>>>(xb, wqkvT, bqkv, cost, sint,
                                                 qhh, khh, vbuf, nullptr, E_);
  vtrans_k<<<dim3(S_/64, H_), 256, 0, stream>>>(vbuf, vth);

  attn_k<<<dim3(S_/64, H_), 256, 0, stream>>>(qhh, khh, vth, relb, aout);

  gemm_k<64,1><<<dim3(8,32), 256, 0, stream>>>(aout, woT, bo, nullptr, nullptr,
                                               nullptr, nullptr, nullptr, out, E_);
}

// Round 3
// 172.203 us; speedup vs baseline: 1.7472x; 1.1498x over previous
//
#include <hip/hip_runtime.h>
#include <hip/hip_bf16.h>

typedef __attribute__((ext_vector_type(8))) short bf16x8;
typedef __attribute__((ext_vector_type(4))) float f32x4;

#define MFMA16(a,b,c) __builtin_amdgcn_mfma_f32_16x16x32_bf16((a),(b),(c),0,0,0)
#define GLDS16(g, l) __builtin_amdgcn_global_load_lds((const __attribute__((address_space(1))) void*)(g), (__attribute__((address_space(3))) void*)(l), 16, 0, 0)

static constexpr int S_ = 2048, E_ = 1024, H_ = 16;
static constexpr float QS = 0.125f * 1.44269504f;   // scale * log2(e)

// ---------------- fused prep: wtrans x4 | conv x | conv rel*8 | rope table | bias ----------------
__global__ __launch_bounds__(256) void prep_k(const float* __restrict__ x, const float* __restrict__ rel,
                                              const float* __restrict__ Wq, const float* __restrict__ Wk,
                                              const float* __restrict__ Wv, const float* __restrict__ Wo,
                                              const float* __restrict__ bq, const float* __restrict__ bk,
                                              const float* __restrict__ bv,
                                              __hip_bfloat16* __restrict__ xb, __hip_bfloat16* __restrict__ relb,
                                              __hip_bfloat16* __restrict__ wqkvT, __hip_bfloat16* __restrict__ woT,
                                              float* __restrict__ bqkv, float* __restrict__ cost,
                                              float* __restrict__ sint) {
  int blk = blockIdx.x, tid = threadIdx.x;
  if (blk < 1024) {
    __shared__ float tile[64][65];
    int wsel = blk >> 8, sub = blk & 255;
    const float* W = wsel == 0 ? Wq : wsel == 1 ? Wk : wsel == 2 ? Wv : Wo;
    __hip_bfloat16* WT = wsel < 3 ? wqkvT + (size_t)wsel * E_ * E_ : woT;
    int bx = sub & 15, by = sub >> 4;
    for (int i = tid; i < 4096; i += 256) {
      int ki = i >> 6, ni = i & 63;
      tile[ki][ni] = W[(size_t)(by*64 + ki) * E_ + bx*64 + ni];
    }
    __syncthreads();
    for (int i = tid; i < 4096; i += 256) {
      int ni = i >> 6, ki = i & 63;
      WT[(size_t)(bx*64 + ni) * E_ + by*64 + ki] = __float2bfloat16(tile[ki][ni]);
    }
  } else if (blk < 3072) {
    int i = (blk - 1024) * 256 + tid;     // < 524288
    float4 v = reinterpret_cast<const float4*>(x)[i];
    xb[4*i+0] = __float2bfloat16(v.x);
    xb[4*i+1] = __float2bfloat16(v.y);
    xb[4*i+2] = __float2bfloat16(v.z);
    xb[4*i+3] = __float2bfloat16(v.w);
  } else if (blk < 3328) {
    int i = (blk - 3072) * 256 + tid;
    if (i < 65520) {
      float4 v = reinterpret_cast<const float4*>(rel)[i];
      relb[4*i+0] = __float2bfloat16(v.x * 8.f);
      relb[4*i+1] = __float2bfloat16(v.y * 8.f);
      relb[4*i+2] = __float2bfloat16(v.z * 8.f);
      relb[4*i+3] = __float2bfloat16(v.w * 8.f);
    }
  } else if (blk < 3584) {
    int idx = (blk - 3328) * 256 + tid;   // s*32 + f
    int f = idx & 31, s = idx >> 5;
    float inv = powf(10000.f, -(float)f * (1.f/32.f));
    float a = (float)s * inv;
    cost[idx] = cosf(a);
    sint[idx] = sinf(a);
  } else {
    int i = (blk - 3584) * 256 + tid;
    if (i < 3072) bqkv[i] = i < 1024 ? bq[i] : (i < 2048 ? bk[i-1024] : bv[i-2048]);
  }
}

// ---------------- GEMM core: C = A @ BT^T, double-buffered global_load_lds ----------------
// MODE 0: fused QKV epilogue (rope; q pre-scaled by QS -> [H][S][64] bf16; v -> [S][E] bf16)
// MODE 1: f32 out + bias
template<int BM, int MODE>
__global__ __launch_bounds__(256) void gemm_k(const __hip_bfloat16* __restrict__ A,
                                              const __hip_bfloat16* __restrict__ BT,
                                              const float* __restrict__ bias,
                                              const float* __restrict__ cost,
                                              const float* __restrict__ sint,
                                              __hip_bfloat16* __restrict__ qhh,
                                              __hip_bfloat16* __restrict__ khh,
                                              __hip_bfloat16* __restrict__ vb,
                                              float* __restrict__ outf,
                                              int K) {
  constexpr int MI = BM/32;
  __shared__ __hip_bfloat16 As[2][BM*64];
  __shared__ __hip_bfloat16 Bs[2][128*64];
  int tid = threadIdx.x, lane = tid & 63, w = tid >> 6;
  int rowq = lane & 15, hi = lane >> 4, ksel = hi << 3;
  int wr = (w >> 1) * (BM/2), wc = (w & 1) * 64;
  int m0 = blockIdx.y * BM, n0 = blockIdx.x * 128;
  int l3 = lane >> 3, l7 = lane & 7;
  f32x4 acc[MI][4] = {};

  auto stage = [&](int k0, int buf) {
    const char* Ap = (const char*)A + ((size_t)(m0 + w*(BM/4)) * K + k0) * 2;
    const char* Bp = (const char*)BT + ((size_t)(n0 + w*32) * K + k0) * 2;
    char* Ad = (char*)&As[buf][w*(BM/4)*64];
    char* Bd = (char*)&Bs[buf][w*32*64];
    for (int i = 0; i < MI; ++i)
      GLDS16(Ap + (size_t)(i*8 + l3)*(K*2) + l7*16, Ad + i*1024);
    for (int i = 0; i < 4; ++i)
      GLDS16(Bp + (size_t)(i*8 + l3)*(K*2) + l7*16, Bd + i*1024);
  };

  stage(0, 0);
  __syncthreads();
  int buf = 0;
  int nk = K >> 6;
  for (int t = 0; t < nk; ++t) {
    if (t + 1 < nk) stage((t+1)*64, buf^1);
    for (int kk = 0; kk < 64; kk += 32) {
      bf16x8 a[MI], b[4];
      for (int i = 0; i < MI; ++i) a[i] = *(const bf16x8*)&As[buf][(wr + i*16 + rowq)*64 + kk + ksel];
      for (int j = 0; j < 4; ++j)  b[j] = *(const bf16x8*)&Bs[buf][(wc + j*16 + rowq)*64 + kk + ksel];
      for (int i = 0; i < MI; ++i)
        for (int j = 0; j < 4; ++j)
          acc[i][j] = MFMA16(a[i], b[j], acc[i][j]);
    }
    __syncthreads();
    buf ^= 1;
  }

  if constexpr (MODE == 0) {
    int matsel = n0 >> 10, ncol = n0 & 1023;
    float bcol[4];
    for (int j = 0; j < 4; ++j) bcol[j] = bias[n0 + wc + j*16 + rowq];
    if (matsel < 2) {
      __hip_bfloat16* dst = matsel ? khh : qhh;
      float qs = matsel ? 1.0f : QS;
      for (int i = 0; i < MI; ++i)
        for (int rg = 0; rg < 4; ++rg) {
          int s = m0 + wr + i*16 + hi*4 + rg;
          for (int j = 0; j < 2; ++j) {
            int colp = ncol + wc + j*16 + rowq;
            int hh = colp >> 6, f = colp & 31;
            float c = cost[s*32 + f], sn = sint[s*32 + f];
            float v1 = acc[i][j][rg]   + bcol[j];
            float v2 = acc[i][j+2][rg] + bcol[j+2];
            dst[((size_t)hh*S_ + s)*64 + f]      = __float2bfloat16((v1*c - v2*sn) * qs);
            dst[((size_t)hh*S_ + s)*64 + f + 32] = __float2bfloat16((v2*c + v1*sn) * qs);
          }
        }
    } else {
      for (int i = 0; i < MI; ++i)
        for (int rg = 0; rg < 4; ++rg) {
          int s = m0 + wr + i*16 + hi*4 + rg;
          for (int j = 0; j < 4; ++j)
            vb[(size_t)s*E_ + ncol + wc + j*16 + rowq] = __float2bfloat16(acc[i][j][rg] + bcol[j]);
        }
    }
  } else {
    for (int i = 0; i < MI; ++i)
      for (int rg = 0; rg < 4; ++rg) {
        int row = m0 + wr + i*16 + hi*4 + rg;
        for (int j = 0; j < 4; ++j) {
          int col = n0 + wc + j*16 + rowq;
          outf[(size_t)row*E_ + col] = acc[i][j][rg] + bias[col];
        }
      }
  }
}

// vb [S][E] bf16 -> vt [H][64][S] bf16
__global__ __launch_bounds__(256) void vtrans_k(const __hip_bfloat16* __restrict__ vb,
                                                __hip_bfloat16* __restrict__ vt) {
  __shared__ __hip_bfloat16 tile[64][72];
  int sb = blockIdx.x, h = blockIdx.y, tid = threadIdx.x;
  int r = tid >> 3, c = (tid & 7) * 8;
  *(int4*)&tile[r][c]    = *(const int4*)(vb + (size_t)(sb*64 + r)*E_ + h*64 + c);
  *(int4*)&tile[r+32][c] = *(const int4*)(vb + (size_t)(sb*64 + r+32)*E_ + h*64 + c);
  __syncthreads();
  int d = tid >> 3, s0 = (tid & 7) * 8;
  __hip_bfloat16 bufa[8], bufb[8];
  for (int j = 0; j < 8; ++j) bufa[j] = tile[s0+j][d];
  for (int j = 0; j < 8; ++j) bufb[j] = tile[s0+j][d+32];
  *(int4*)(vt + ((size_t)h*64 + d)*S_ + sb*64 + s0)    = *(int4*)bufa;
  *(int4*)(vt + ((size_t)h*64 + d+32)*S_ + sb*64 + s0) = *(int4*)bufb;
}

// ---------------- fused causal attention with rel-pos bias (exp2 domain) ----------------
// qh: [H][S][64] bf16 rotated, pre-scaled by QS; kh: [H][S][64] rotated; vt: [H][64][S];
// relb: [4095][64] bf16 (x8); out: [S][E] bf16
__global__ __launch_bounds__(256) void attn_k(const __hip_bfloat16* __restrict__ qh,
                                              const __hip_bfloat16* __restrict__ kh,
                                              const __hip_bfloat16* __restrict__ vt,
                                              const __hip_bfloat16* __restrict__ relb,
                                              __hip_bfloat16* __restrict__ attn_out) {
  // balanced pairing: blocks x and x+256 (same CU under breadth-first RR) get qb and 31-qb
  int bx = blockIdx.x;
  int qb, h;
  if (bx < 256) { qb = bx >> 4;              h = bx & 15; }
  else          { qb = 31 - ((bx-256) >> 4); h = (bx-256) & 15; }
  int tid = threadIdx.x, lane = tid & 63, w = tid >> 6;
  int i0w = qb*64 + w*16;
  __shared__ __hip_bfloat16 Ks[2][4096];      // [64][64] linear, XOR-swizzled content
  __shared__ __hip_bfloat16 Vs[2][4096];      // [d][key] linear, XOR-swizzled content
  __shared__ __hip_bfloat16 WP[4][16][88];    // union: Wt window (cols 0..79) then P (cols 0..63)
  int rowq = lane & 15, hi = lane >> 4, ksel = hi << 3;
  int l3 = lane >> 3, l7 = lane & 7;
  int swz = (l7*16) ^ (l3 << 4);

  const __hip_bfloat16* qrow = qh + ((size_t)h*S_ + i0w + rowq)*64 + ksel;
  bf16x8 q0 = *(const bf16x8*)(qrow);
  bf16x8 q1 = *(const bf16x8*)(qrow + 32);

  f32x4 o[4] = {};
  float mrow[4], lrow[4];
  for (int i = 0; i < 4; ++i) { mrow[i] = -1e30f; lrow[i] = 0.f; }

  auto stage = [&](int t, int buf) {
    int j0 = t * 64;
    const char* kp = (const char*)(kh + ((size_t)h*S_ + j0 + w*16)*64);
    const char* vp = (const char*)(vt + ((size_t)(h*64 + w*16))*S_ + j0);
    char* kd = (char*)&Ks[buf][w*16*64];
    char* vd = (char*)&Vs[buf][w*16*64];
    for (int i = 0; i < 2; ++i) {
      GLDS16(kp + (size_t)(i*8 + l3)*128  + swz, kd + i*1024);
      GLDS16(vp + (size_t)(i*8 + l3)*4096 + swz, vd + i*1024);
    }
  };

  int pcol0 = ((hi*16)      ^ ((rowq & 7) << 4)) >> 1;
  int pcol1 = ((64 + hi*16) ^ ((rowq & 7) << 4)) >> 1;

  int nt = qb + 1;
  stage(0, 0);
  __syncthreads();
  int buf = 0;
  for (int t = 0; t < nt; ++t) {
    int j0 = t * 64;
    if (t + 1 < nt) stage(t+1, buf^1);

    // QK^T and rel window (both in exp2 domain already)
    f32x4 sa[4] = {};
    f32x4 wtacc[5] = {};
    int base = j0 - i0w + 2032;   // 2047 - 15
    __builtin_amdgcn_s_setprio(1);
    for (int kk = 0; kk < 2; ++kk) {
      bf16x8 a = kk ? q1 : q0;
      int pc = kk ? pcol1 : pcol0;
      for (int nf = 0; nf < 4; ++nf) {
        bf16x8 b = *(const bf16x8*)&Ks[buf][(nf*16 + rowq)*64 + pc];
        sa[nf] = MFMA16(a, b, sa[nf]);
      }
      for (int nf = 0; nf < 5; ++nf) {
        const __hip_bfloat16* rp = relb + (size_t)(base + nf*16 + rowq)*64 + kk*32 + ksel;
        wtacc[nf] = MFMA16(a, *(const bf16x8*)rp, wtacc[nf]);
      }
    }
    __builtin_amdgcn_s_setprio(0);
    for (int nf = 0; nf < 5; ++nf)
      for (int rg = 0; rg < 4; ++rg)
        WP[w][hi*4 + rg][nf*16 + rowq] = __float2bfloat16(wtacc[nf][rg]);

    // online softmax in exp2 domain; lrow kept as per-lane partial (no sum-tree per tile)
    float alpha[4];
    bool last = (t == nt - 1);
    for (int rg = 0; rg < 4; ++rg) {
      int row = hi*4 + rg;
      float sv[4];
      for (int nf = 0; nf < 4; ++nf) {
        int s = nf*16 + rowq;
        float v = sa[nf][rg] + __bfloat162float(WP[w][row][s - row + 15]);
        if (last && s > w*16 + row) v = -1e30f;
        sv[nf] = v;
      }
      float tm = fmaxf(fmaxf(sv[0], sv[1]), fmaxf(sv[2], sv[3]));
      for (int mk = 1; mk < 16; mk <<= 1) tm = fmaxf(tm, __shfl_xor(tm, mk));
      float mnew = fmaxf(mrow[rg], tm);
      float al = exp2f(mrow[rg] - mnew);
      float ls = 0.f;
      for (int nf = 0; nf < 4; ++nf) {
        float p = exp2f(sv[nf] - mnew);
        ls += p;
        WP[w][row][nf*16 + rowq] = __float2bfloat16(p);
      }
      lrow[rg] = lrow[rg] * al + ls;
      mrow[rg] = mnew;
      alpha[rg] = al;
    }
    for (int df = 0; df < 4; ++df)
      for (int rg = 0; rg < 4; ++rg) o[df][rg] *= alpha[rg];

    // PV
    __builtin_amdgcn_s_setprio(1);
    for (int kk = 0; kk < 2; ++kk) {
      bf16x8 a = *(const bf16x8*)&WP[w][rowq][kk*32 + ksel];
      int pc = kk ? pcol1 : pcol0;
      for (int df = 0; df < 4; ++df) {
        bf16x8 b = *(const bf16x8*)&Vs[buf][(df*16 + rowq)*64 + pc];
        o[df] = MFMA16(a, b, o[df]);
      }
    }
    __builtin_amdgcn_s_setprio(0);
    __syncthreads();
    buf ^= 1;
  }

  for (int rg = 0; rg < 4; ++rg) {
    float l = lrow[rg];
    for (int mk = 1; mk < 16; mk <<= 1) l += __shfl_xor(l, mk);
    lrow[rg] = 1.0f / l;
  }
  for (int df = 0; df < 4; ++df)
    for (int rg = 0; rg < 4; ++rg) {
      int row = i0w + hi*4 + rg;
      int col = h*64 + df*16 + rowq;
      attn_out[(size_t)row * E_ + col] = __float2bfloat16(o[df][rg] * lrow[rg]);
    }
}

// ---------------- launcher ----------------

extern "C" void kernel_launch(void* const* d_in, const int* in_sizes, int n_in,
                              void* d_out, int out_size, void* d_ws, size_t ws_size,
                              hipStream_t stream) {
  const float* x   = (const float*)d_in[0];
  const float* Wq  = (const float*)d_in[2];
  const float* bq  = (const float*)d_in[3];
  const float* Wk  = (const float*)d_in[4];
  const float* bk  = (const float*)d_in[5];
  const float* Wv  = (const float*)d_in[6];
  const float* bv  = (const float*)d_in[7];
  const float* Wo  = (const float*)d_in[8];
  const float* bo  = (const float*)d_in[9];
  const float* rel = (const float*)d_in[10];
  float* out = (float*)d_out;

  char* ws = (char*)d_ws;
  size_t off = 0;
  auto alloc = [&](size_t bytes) -> void* {
    void* p = ws + off;
    off = (off + bytes + 255) & ~(size_t)255;
    return p;
  };
  __hip_bfloat16* xb    = (__hip_bfloat16*)alloc((size_t)S_*E_*2);
  __hip_bfloat16* wqkvT = (__hip_bfloat16*)alloc((size_t)3*E_*E_*2);
  __hip_bfloat16* woT   = (__hip_bfloat16*)alloc((size_t)E_*E_*2);
  __hip_bfloat16* relb  = (__hip_bfloat16*)alloc((size_t)4095*64*2);
  float* bqkv = (float*)alloc((size_t)3072*4);
  float* cost = (float*)alloc((size_t)S_*32*4);
  float* sint = (float*)alloc((size_t)S_*32*4);
  __hip_bfloat16* qhh  = (__hip_bfloat16*)alloc((size_t)S_*E_*2);
  __hip_bfloat16* khh  = (__hip_bfloat16*)alloc((size_t)S_*E_*2);
  __hip_bfloat16* vbuf = (__hip_bfloat16*)alloc((size_t)S_*E_*2);
  __hip_bfloat16* vth  = (__hip_bfloat16*)alloc((size_t)S_*E_*2);
  __hip_bfloat16* aout = (__hip_bfloat16*)alloc((size_t)S_*E_*2);

  prep_k<<<3596, 256, 0, stream>>>(x, rel, Wq, Wk, Wv, Wo, bq, bk, bv,
                                   xb, relb, wqkvT, woT, bqkv, cost, sint);

  gemm_k<128,0><<<dim3(24,16), 256, 0, stream>>>(xb, wqkvT, bqkv, cost, sint,
                                                 qhh, khh, vbuf, nullptr, E_);
  vtrans_k<<<dim3(S_/64, H_), 256, 0, stream>>>(vbuf, vth);

  attn_k<<<512, 256, 0, stream>>>(qhh, khh, vth, relb, aout);

  gemm_k<64,1><<<dim3(8,32), 256, 0, stream>>>(aout, woT, bo, nullptr, nullptr,
                                               nullptr, nullptr, nullptr, out, E_);
}

// Round 4
// 141.239 us; speedup vs baseline: 2.1302x; 1.2192x over previous
//
#include <hip/hip_runtime.h>
#include <hip/hip_bf16.h>

typedef __attribute__((ext_vector_type(8))) short bf16x8;
typedef __attribute__((ext_vector_type(4))) float f32x4;

#define MFMA16(a,b,c) __builtin_amdgcn_mfma_f32_16x16x32_bf16((a),(b),(c),0,0,0)
#define GLDS16(g, l) __builtin_amdgcn_global_load_lds((const __attribute__((address_space(1))) void*)(g), (__attribute__((address_space(3))) void*)(l), 16, 0, 0)

static constexpr int S_ = 2048, E_ = 1024, H_ = 16;
static constexpr float QS = 0.125f * 1.44269504f;   // scale * log2(e)

__device__ __forceinline__ unsigned pk2(float a, float b) {
  __hip_bfloat16 ba = __float2bfloat16(a), bb = __float2bfloat16(b);
  return (unsigned)*(unsigned short*)&ba | ((unsigned)*(unsigned short*)&bb << 16);
}
__device__ __forceinline__ float ubf(unsigned short u) {
  return __uint_as_float((unsigned)u << 16);
}

// ---------------- fused prep ----------------
__global__ __launch_bounds__(256) void prep_k(const float* __restrict__ x, const float* __restrict__ rel,
                                              const float* __restrict__ Wq, const float* __restrict__ Wk,
                                              const float* __restrict__ Wv, const float* __restrict__ Wo,
                                              const float* __restrict__ bq, const float* __restrict__ bk,
                                              const float* __restrict__ bv,
                                              __hip_bfloat16* __restrict__ xb, __hip_bfloat16* __restrict__ relb,
                                              __hip_bfloat16* __restrict__ wqkvT, __hip_bfloat16* __restrict__ woT,
                                              float* __restrict__ bqkv, float* __restrict__ cost,
                                              float* __restrict__ sint) {
  int blk = blockIdx.x, tid = threadIdx.x;
  if (blk < 1024) {
    __shared__ float tile[64][65];
    int wsel = blk >> 8, sub = blk & 255;
    const float* W = wsel == 0 ? Wq : wsel == 1 ? Wk : wsel == 2 ? Wv : Wo;
    __hip_bfloat16* WT = wsel < 3 ? wqkvT + (size_t)wsel * E_ * E_ : woT;
    int bx = sub & 15, by = sub >> 4;
    for (int i = tid; i < 4096; i += 256) {
      int ki = i >> 6, ni = i & 63;
      tile[ki][ni] = W[(size_t)(by*64 + ki) * E_ + bx*64 + ni];
    }
    __syncthreads();
    for (int i = tid; i < 4096; i += 256) {
      int ni = i >> 6, ki = i & 63;
      WT[(size_t)(bx*64 + ni) * E_ + by*64 + ki] = __float2bfloat16(tile[ki][ni]);
    }
  } else if (blk < 3072) {
    int i = (blk - 1024) * 256 + tid;
    float4 v = reinterpret_cast<const float4*>(x)[i];
    xb[4*i+0] = __float2bfloat16(v.x);
    xb[4*i+1] = __float2bfloat16(v.y);
    xb[4*i+2] = __float2bfloat16(v.z);
    xb[4*i+3] = __float2bfloat16(v.w);
  } else if (blk < 3328) {
    int i = (blk - 3072) * 256 + tid;
    if (i < 65520) {
      float4 v = reinterpret_cast<const float4*>(rel)[i];
      relb[4*i+0] = __float2bfloat16(v.x * 8.f);
      relb[4*i+1] = __float2bfloat16(v.y * 8.f);
      relb[4*i+2] = __float2bfloat16(v.z * 8.f);
      relb[4*i+3] = __float2bfloat16(v.w * 8.f);
    }
  } else if (blk < 3584) {
    int idx = (blk - 3328) * 256 + tid;
    int f = idx & 31, s = idx >> 5;
    float inv = powf(10000.f, -(float)f * (1.f/32.f));
    float a = (float)s * inv;
    cost[idx] = cosf(a);
    sint[idx] = sinf(a);
  } else {
    int i = (blk - 3584) * 256 + tid;
    if (i < 3072) bqkv[i] = i < 1024 ? bq[i] : (i < 2048 ? bk[i-1024] : bv[i-2048]);
  }
}

// ---------------- GEMM core (unchanged structure) ----------------
template<int BM, int MODE>
__global__ __launch_bounds__(256) void gemm_k(const __hip_bfloat16* __restrict__ A,
                                              const __hip_bfloat16* __restrict__ BT,
                                              const float* __restrict__ bias,
                                              const float* __restrict__ cost,
                                              const float* __restrict__ sint,
                                              __hip_bfloat16* __restrict__ qhh,
                                              __hip_bfloat16* __restrict__ khh,
                                              __hip_bfloat16* __restrict__ vb,
                                              float* __restrict__ outf,
                                              int K) {
  constexpr int MI = BM/32;
  __shared__ __hip_bfloat16 As[2][BM*64];
  __shared__ __hip_bfloat16 Bs[2][128*64];
  int tid = threadIdx.x, lane = tid & 63, w = tid >> 6;
  int rowq = lane & 15, hi = lane >> 4, ksel = hi << 3;
  int wr = (w >> 1) * (BM/2), wc = (w & 1) * 64;
  int m0 = blockIdx.y * BM, n0 = blockIdx.x * 128;
  int l3 = lane >> 3, l7 = lane & 7;
  f32x4 acc[MI][4] = {};

  auto stage = [&](int k0, int buf) {
    const char* Ap = (const char*)A + ((size_t)(m0 + w*(BM/4)) * K + k0) * 2;
    const char* Bp = (const char*)BT + ((size_t)(n0 + w*32) * K + k0) * 2;
    char* Ad = (char*)&As[buf][w*(BM/4)*64];
    char* Bd = (char*)&Bs[buf][w*32*64];
    for (int i = 0; i < MI; ++i)
      GLDS16(Ap + (size_t)(i*8 + l3)*(K*2) + l7*16, Ad + i*1024);
    for (int i = 0; i < 4; ++i)
      GLDS16(Bp + (size_t)(i*8 + l3)*(K*2) + l7*16, Bd + i*1024);
  };

  stage(0, 0);
  __syncthreads();
  int buf = 0;
  int nk = K >> 6;
  for (int t = 0; t < nk; ++t) {
    if (t + 1 < nk) stage((t+1)*64, buf^1);
    for (int kk = 0; kk < 64; kk += 32) {
      bf16x8 a[MI], b[4];
      for (int i = 0; i < MI; ++i) a[i] = *(const bf16x8*)&As[buf][(wr + i*16 + rowq)*64 + kk + ksel];
      for (int j = 0; j < 4; ++j)  b[j] = *(const bf16x8*)&Bs[buf][(wc + j*16 + rowq)*64 + kk + ksel];
      for (int i = 0; i < MI; ++i)
        for (int j = 0; j < 4; ++j)
          acc[i][j] = MFMA16(a[i], b[j], acc[i][j]);
    }
    __syncthreads();
    buf ^= 1;
  }

  if constexpr (MODE == 0) {
    int matsel = n0 >> 10, ncol = n0 & 1023;
    float bcol[4];
    for (int j = 0; j < 4; ++j) bcol[j] = bias[n0 + wc + j*16 + rowq];
    if (matsel < 2) {
      __hip_bfloat16* dst = matsel ? khh : qhh;
      float qs = matsel ? 1.0f : QS;
      for (int i = 0; i < MI; ++i)
        for (int rg = 0; rg < 4; ++rg) {
          int s = m0 + wr + i*16 + hi*4 + rg;
          for (int j = 0; j < 2; ++j) {
            int colp = ncol + wc + j*16 + rowq;
            int hh = colp >> 6, f = colp & 31;
            float c = cost[s*32 + f], sn = sint[s*32 + f];
            float v1 = acc[i][j][rg]   + bcol[j];
            float v2 = acc[i][j+2][rg] + bcol[j+2];
            dst[((size_t)hh*S_ + s)*64 + f]      = __float2bfloat16((v1*c - v2*sn) * qs);
            dst[((size_t)hh*S_ + s)*64 + f + 32] = __float2bfloat16((v2*c + v1*sn) * qs);
          }
        }
    } else {
      for (int i = 0; i < MI; ++i)
        for (int rg = 0; rg < 4; ++rg) {
          int s = m0 + wr + i*16 + hi*4 + rg;
          for (int j = 0; j < 4; ++j)
            vb[(size_t)s*E_ + ncol + wc + j*16 + rowq] = __float2bfloat16(acc[i][j][rg] + bcol[j]);
        }
    }
  } else {
    for (int i = 0; i < MI; ++i)
      for (int rg = 0; rg < 4; ++rg) {
        int row = m0 + wr + i*16 + hi*4 + rg;
        for (int j = 0; j < 4; ++j) {
          int col = n0 + wc + j*16 + rowq;
          outf[(size_t)row*E_ + col] = acc[i][j][rg] + bias[col];
        }
      }
  }
}

// vb [S][E] bf16 -> vt [H][64][S] bf16
__global__ __launch_bounds__(256) void vtrans_k(const __hip_bfloat16* __restrict__ vb,
                                                __hip_bfloat16* __restrict__ vt) {
  __shared__ __hip_bfloat16 tile[64][72];
  int sb = blockIdx.x, h = blockIdx.y, tid = threadIdx.x;
  int r = tid >> 3, c = (tid & 7) * 8;
  *(int4*)&tile[r][c]    = *(const int4*)(vb + (size_t)(sb*64 + r)*E_ + h*64 + c);
  *(int4*)&tile[r+32][c] = *(const int4*)(vb + (size_t)(sb*64 + r+32)*E_ + h*64 + c);
  __syncthreads();
  int d = tid >> 3, s0 = (tid & 7) * 8;
  __hip_bfloat16 bufa[8], bufb[8];
  for (int j = 0; j < 8; ++j) bufa[j] = tile[s0+j][d];
  for (int j = 0; j < 8; ++j) bufb[j] = tile[s0+j][d+32];
  *(int4*)(vt + ((size_t)h*64 + d)*S_ + sb*64 + s0)    = *(int4*)bufa;
  *(int4*)(vt + ((size_t)h*64 + d+32)*S_ + sb*64 + s0) = *(int4*)bufb;
}

// ---------------- attention: swapped-MFMA lane-local softmax, split-K, paired phases ----------
// block b: h=b&15, p=b>>4. phase0: qb=p, tiles [0, ceil((p+1)/2)) -> slot0
//                          phase1: qb=31-p, tiles [ceil((33-p-1+1)/2)=..., T) -> slot1
// opart[slot][S][E] bf16 unnormalized o; ml[slot][S][H] float2(m, l)
__global__ __launch_bounds__(256,2) void attn_k(const __hip_bfloat16* __restrict__ qh,
                                                const __hip_bfloat16* __restrict__ kh,
                                                const __hip_bfloat16* __restrict__ vt,
                                                const __hip_bfloat16* __restrict__ relb,
                                                __hip_bfloat16* __restrict__ opart,
                                                float2* __restrict__ ml) {
  int h = blockIdx.x & 15, p = blockIdx.x >> 4;
  int tid = threadIdx.x, lane = tid & 63, w = tid >> 6;
  int rowq = lane & 15, hi = lane >> 4, ksel = hi << 3;
  int l3 = lane >> 3, l7 = lane & 7;
  int swz = (l7*16) ^ (l3 << 4);
  __shared__ __hip_bfloat16 Ks[2][4096];
  __shared__ __hip_bfloat16 Vs[2][4096];
  __shared__ unsigned short WPs[4][16][96];   // per-wave: rel-window W then P (cols 0..63)
  int pcol0 = ((hi*16)      ^ ((rowq & 7) << 4)) >> 1;
  int pcol1 = ((64 + hi*16) ^ ((rowq & 7) << 4)) >> 1;

  for (int ph = 0; ph < 2; ++ph) {
    int qb = ph ? 31 - p : p;
    int T = qb + 1;
    int t0 = ph ? (T + 1) >> 1 : 0;
    int t1 = ph ? T : (T + 1) >> 1;
    int i0w = qb*64 + w*16;

    const __hip_bfloat16* qrow = qh + ((size_t)h*S_ + i0w + rowq)*64 + ksel;
    bf16x8 q0 = *(const bf16x8*)(qrow);
    bf16x8 q1 = *(const bf16x8*)(qrow + 32);
    f32x4 o[4] = {};
    float m = -1e30f, l = 0.f;

    auto stage = [&](int t, int buf) {
      int j0 = t * 64;
      const char* kp = (const char*)(kh + ((size_t)h*S_ + j0 + w*16)*64);
      const char* vp = (const char*)(vt + ((size_t)(h*64 + w*16))*S_ + j0);
      char* kd = (char*)&Ks[buf][w*16*64];
      char* vd = (char*)&Vs[buf][w*16*64];
      for (int i = 0; i < 2; ++i) {
        GLDS16(kp + (size_t)(i*8 + l3)*128  + swz, kd + i*1024);
        GLDS16(vp + (size_t)(i*8 + l3)*4096 + swz, vd + i*1024);
      }
    };
    auto ldrel = [&](int t, bf16x8* r) {
      const __hip_bfloat16* rp = relb + (size_t)(t*64 - i0w + 2032 + rowq)*64 + ksel;
      #pragma unroll
      for (int nf = 0; nf < 5; ++nf) {
        r[nf*2]   = *(const bf16x8*)(rp + nf*1024);
        r[nf*2+1] = *(const bf16x8*)(rp + nf*1024 + 32);
      }
    };

    if (t0 < t1) {
      bf16x8 rc[10], rn[10];
      ldrel(t0, rc);
      stage(t0, 0);
      __syncthreads();
      int buf = 0;
      for (int t = t0; t < t1; ++t) {
        bool more = (t + 1 < t1);
        if (more) { stage(t+1, buf^1); ldrel(t+1, rn); }

        f32x4 sa[4] = {};
        f32x4 wt[5] = {};
        __builtin_amdgcn_s_setprio(1);
        for (int kk = 0; kk < 2; ++kk) {
          bf16x8 qf = kk ? q1 : q0;
          int pc = kk ? pcol1 : pcol0;
          for (int nf = 0; nf < 4; ++nf) {
            bf16x8 kf = *(const bf16x8*)&Ks[buf][(nf*16 + rowq)*64 + pc];
            sa[nf] = MFMA16(kf, qf, sa[nf]);        // D[key][q]: lane-local q row
          }
          for (int nf = 0; nf < 5; ++nf)
            wt[nf] = MFMA16(rc[nf*2+kk], qf, wt[nf]); // D[relrow][q]
        }
        __builtin_amdgcn_s_setprio(0);

        // store W window (bf16, packed b64)
        #pragma unroll
        for (int nf = 0; nf < 5; ++nf) {
          uint2 u = { pk2(wt[nf][0], wt[nf][1]), pk2(wt[nf][2], wt[nf][3]) };
          *(uint2*)&WPs[w][rowq][nf*16 + hi*4] = u;
        }

        // gather bias + softmax (all lane-local for q=rowq)
        float sv[4][4];
        float tm = -1e30f;
        bool diag = (t == qb);
        #pragma unroll
        for (int nf = 0; nf < 4; ++nf)
          #pragma unroll
          for (int rg = 0; rg < 4; ++rg) {
            int kl = nf*16 + hi*4 + rg;
            float v = sa[nf][rg] + ubf(WPs[w][rowq][kl - rowq + 15]);
            if (diag && kl > w*16 + rowq) v = -1e30f;
            sv[nf][rg] = v;
            tm = fmaxf(tm, v);
          }
        tm = fmaxf(tm, __shfl_xor(tm, 16));
        tm = fmaxf(tm, __shfl_xor(tm, 32));
        float mnew = fmaxf(m, tm);
        float al = exp2f(m - mnew);
        m = mnew;
        float ls = 0.f;
        float pe[4][4];
        #pragma unroll
        for (int nf = 0; nf < 4; ++nf)
          #pragma unroll
          for (int rg = 0; rg < 4; ++rg) {
            float e = exp2f(sv[nf][rg] - mnew);
            pe[nf][rg] = e;
            ls += e;
          }
        l = l * al + ls;
        #pragma unroll
        for (int nf = 0; nf < 4; ++nf) {
          uint2 u = { pk2(pe[nf][0], pe[nf][1]), pk2(pe[nf][2], pe[nf][3]) };
          *(uint2*)&WPs[w][rowq][nf*16 + hi*4] = u;
        }
        float alq[4];
        #pragma unroll
        for (int rg = 0; rg < 4; ++rg) alq[rg] = __shfl(al, hi*4 + rg, 16);
        #pragma unroll
        for (int df = 0; df < 4; ++df)
          #pragma unroll
          for (int rg = 0; rg < 4; ++rg) o[df][rg] *= alq[rg];

        // PV
        __builtin_amdgcn_s_setprio(1);
        for (int kk = 0; kk < 2; ++kk) {
          bf16x8 a = *(const bf16x8*)&WPs[w][rowq][kk*32 + ksel];
          int pc = kk ? pcol1 : pcol0;
          for (int df = 0; df < 4; ++df) {
            bf16x8 b = *(const bf16x8*)&Vs[buf][(df*16 + rowq)*64 + pc];
            o[df] = MFMA16(a, b, o[df]);
          }
        }
        __builtin_amdgcn_s_setprio(0);
        __syncthreads();
        buf ^= 1;
        if (more) {
          #pragma unroll
          for (int i = 0; i < 10; ++i) rc[i] = rn[i];
        }
      }
    }

    // phase epilogue: partial o (unnormalized), m, l
    float lt = l;
    lt += __shfl_xor(lt, 16);
    lt += __shfl_xor(lt, 32);
    if (lane < 16) ml[((size_t)ph*S_ + i0w + rowq)*H_ + h] = make_float2(m, lt);
    #pragma unroll
    for (int df = 0; df < 4; ++df)
      #pragma unroll
      for (int rg = 0; rg < 4; ++rg)
        opart[(size_t)ph*S_*E_ + (size_t)(i0w + hi*4 + rg)*E_ + h*64 + df*16 + rowq] =
            __float2bfloat16(o[df][rg]);
    __syncthreads();
  }
}

// ---------------- combine split-K partials -> aout bf16 ----------------
__global__ __launch_bounds__(256) void combine_k(const __hip_bfloat16* __restrict__ opart,
                                                 const float2* __restrict__ ml,
                                                 __hip_bfloat16* __restrict__ aout) {
  int r = blockIdx.x, tid = threadIdx.x;
  int c = tid * 4, h = c >> 6;
  float2 a0 = ml[(size_t)r*H_ + h];
  float2 a1 = ml[(size_t)(S_ + r)*H_ + h];
  float M = fmaxf(a0.x, a1.x);
  float w0 = exp2f(a0.x - M), w1 = exp2f(a1.x - M);
  float dinv = 1.0f / (w0*a0.y + w1*a1.y);
  w0 *= dinv; w1 *= dinv;
  const unsigned short* o0 = (const unsigned short*)opart + (size_t)r*E_ + c;
  const unsigned short* o1 = o0 + (size_t)S_*E_;
  ushort4 u0 = *(const ushort4*)o0;
  ushort4 u1 = *(const ushort4*)o1;
  __hip_bfloat16 res[4];
  res[0] = __float2bfloat16(w0*ubf(u0.x) + w1*ubf(u1.x));
  res[1] = __float2bfloat16(w0*ubf(u0.y) + w1*ubf(u1.y));
  res[2] = __float2bfloat16(w0*ubf(u0.z) + w1*ubf(u1.z));
  res[3] = __float2bfloat16(w0*ubf(u0.w) + w1*ubf(u1.w));
  *(ushort4*)((unsigned short*)aout + (size_t)r*E_ + c) = *(ushort4*)res;
}

// ---------------- launcher ----------------
extern "C" void kernel_launch(void* const* d_in, const int* in_sizes, int n_in,
                              void* d_out, int out_size, void* d_ws, size_t ws_size,
                              hipStream_t stream) {
  const float* x   = (const float*)d_in[0];
  const float* Wq  = (const float*)d_in[2];
  const float* bq  = (const float*)d_in[3];
  const float* Wk  = (const float*)d_in[4];
  const float* bk  = (const float*)d_in[5];
  const float* Wv  = (const float*)d_in[6];
  const float* bv  = (const float*)d_in[7];
  const float* Wo  = (const float*)d_in[8];
  const float* bo  = (const float*)d_in[9];
  const float* rel = (const float*)d_in[10];
  float* out = (float*)d_out;

  char* ws = (char*)d_ws;
  size_t off = 0;
  auto alloc = [&](size_t bytes) -> void* {
    void* p = ws + off;
    off = (off + bytes + 255) & ~(size_t)255;
    return p;
  };
  __hip_bfloat16* xb    = (__hip_bfloat16*)alloc((size_t)S_*E_*2);
  __hip_bfloat16* wqkvT = (__hip_bfloat16*)alloc((size_t)3*E_*E_*2);
  __hip_bfloat16* woT   = (__hip_bfloat16*)alloc((size_t)E_*E_*2);
  __hip_bfloat16* relb  = (__hip_bfloat16*)alloc((size_t)4095*64*2);
  float* bqkv = (float*)alloc((size_t)3072*4);
  float* cost = (float*)alloc((size_t)S_*32*4);
  float* sint = (float*)alloc((size_t)S_*32*4);
  __hip_bfloat16* qhh  = (__hip_bfloat16*)alloc((size_t)S_*E_*2);
  __hip_bfloat16* khh  = (__hip_bfloat16*)alloc((size_t)S_*E_*2);
  __hip_bfloat16* vbuf = (__hip_bfloat16*)alloc((size_t)S_*E_*2);
  __hip_bfloat16* vth  = (__hip_bfloat16*)alloc((size_t)S_*E_*2);
  __hip_bfloat16* aout = (__hip_bfloat16*)alloc((size_t)S_*E_*2);

  // split-K partials alias dead regions (both consumed before attn writes them):
  __hip_bfloat16* opart = (__hip_bfloat16*)ws;   // 8 MB over xb+wqkvT (dead after QKV gemm)
  float2* ml = (float2*)vbuf;                    // 512 KB over vbuf (dead after vtrans)

  prep_k<<<3596, 256, 0, stream>>>(x, rel, Wq, Wk, Wv, Wo, bq, bk, bv,
                                   xb, relb, wqkvT, woT, bqkv, cost, sint);

  gemm_k<128,0><<<dim3(24,16), 256, 0, stream>>>(xb, wqkvT, bqkv, cost, sint,
                                                 qhh, khh, vbuf, nullptr, E_);
  vtrans_k<<<dim3(S_/64, H_), 256, 0, stream>>>(vbuf, vth);

  attn_k<<<512, 256, 0, stream>>>(qhh, khh, vth, relb, opart, ml);
  combine_k<<<S_, 256, 0, stream>>>(opart, ml, aout);

  gemm_k<64,1><<<dim3(8,32), 256, 0, stream>>>(aout, woT, bo, nullptr, nullptr,
                                               nullptr, nullptr, nullptr, out, E_);
}